// Round 1
// baseline (68.141 us; speedup 1.0000x reference)
//
#include <hip/hip_runtime.h>
#include <math.h>

// Problem constants (from reference setup_inputs)
#define N_  2
#define C_  64
#define S_  4
#define H_  64
#define W_  44
#define HW_       (H_ * W_)          // 2816
#define CH_STRIDE (S_ * HW_)         // 11264 elements between channels
#define NSTRIDE   (C_ * S_ * HW_)    // 720896 elements between n-batches

typedef _Float16 h8 __attribute__((ext_vector_type(8)));
typedef float    f4 __attribute__((ext_vector_type(4)));

// Round 10: split the f32->f16 repack out of the hot kernel.
//
// Kernel 1 (repack): one pass over f0/f1, writes f16 packed arrays in the
// exact MFMA fragment layouts the round-9 kernel staged into LDS:
//   pk1[(b*64+row)*4096 + (c8*64 + xi)*8 + j]  (xi 0..63, col=xi-8, halo zeroed)
//   pk0[(b*64+y)*3072   + (c8*48 + x )*8 + j]  (x 0..47, zero-pad 44..47)
// ~18.5 MB of traffic -> memory-bound, a few us.
//
// Kernel 2 (flow_main): per (b,y) block, 7 waves. NO LDS staging: each wave's
// A fragments (6 x b128) and B fragments (12 x b128) are per-lane global
// loads from the packed arrays (L2-resident: ~1 MB per XCD with the b=blk&7
// batch->XCD pinning). No first barrier, LDS = corr only (8.6 KB), low VGPR.
// MFMA indexing identical to the harness-verified round-9 kernel.
__global__ __launch_bounds__(512) void repack_kernel(
    const float* __restrict__ f0,
    const float* __restrict__ f1,
    _Float16* __restrict__ pk0,
    _Float16* __restrict__ pk1)
{
    const int tid = threadIdx.x;          // 0..511
    const int c8  = tid >> 6;             // channel group 0..7
    const int xi  = tid & 63;             // padded column 0..63
    const int b   = blockIdx.x & 7;
    const int y   = blockIdx.x >> 3;
    const int n_idx = b >> 2;
    const int s_idx = b & 3;
    const int base  = n_idx * NSTRIDE + s_idx * HW_ + y * W_;

    // ---- f1 row y, padded column xi (col = xi-8), channels c8*8..c8*8+7 ----
    {
        const int col  = xi - 8;
        const bool vld = (col >= 0) && (col < W_);
        const int cc   = min(max(col, 0), W_ - 1);
        const float* p = f1 + base + cc;
        float v[8];
        #pragma unroll
        for (int j = 0; j < 8; ++j)
            v[j] = p[(size_t)(c8 * 8 + j) * CH_STRIDE];
        h8 pk;
        #pragma unroll
        for (int j = 0; j < 8; ++j)
            pk[j] = vld ? (_Float16)v[j] : (_Float16)0.0f;
        *(h8*)&pk1[(((size_t)(b * 64 + y) * 8 + c8) << 9) + xi * 8] = pk;
    }

    // ---- f0 row y, x = xi (0..47, zero-pad 44..47) ----
    if (xi < 48) {
        const bool vld = (xi < W_);
        const int xc   = min(xi, W_ - 1);
        const float* p = f0 + base + xc;
        float v[8];
        #pragma unroll
        for (int j = 0; j < 8; ++j)
            v[j] = p[(size_t)(c8 * 8 + j) * CH_STRIDE];
        h8 pk;
        #pragma unroll
        for (int j = 0; j < 8; ++j)
            pk[j] = vld ? (_Float16)v[j] : (_Float16)0.0f;
        *(h8*)&pk0[(size_t)(b * 64 + y) * 3072 + (c8 * 48 + xi) * 8] = pk;
    }
}

__global__ __launch_bounds__(448) void flow_main(
    const _Float16* __restrict__ pk0,
    const _Float16* __restrict__ pk1,
    float* __restrict__ out)
{
    const int lane = threadIdx.x & 63;
    const int w    = threadIdx.x >> 6;      // 0..6 (one wave per f1 row)
    const int b    = blockIdx.x & 7;        // batch pinned per XCD slot
    const int y    = blockIdx.x >> 3;
    const int n_idx = b >> 2;
    const int s_idx = b & 3;

    __shared__ float corr[W_][49];          // 8624 B — the only LDS

    const int row = y + w - 3;
    if (row >= 0 && row < H_) {
        const int quad = lane >> 4;
        const int l16  = lane & 15;

        const h8* A = (const h8*)(pk0 + (size_t)(b * 64 + y) * 3072);
        const h8* B = (const h8*)(pk1 + ((size_t)(b * 64 + row) << 12));

        // Issue all fragment loads up front (independent; one vmcnt drain).
        h8 afr[3][2], bfr[3][2][2];
        #pragma unroll
        for (int mi = 0; mi < 3; ++mi) {
            #pragma unroll
            for (int kh = 0; kh < 2; ++kh) {
                afr[mi][kh] = A[(kh * 4 + quad) * 48 + mi * 16 + l16];
                #pragma unroll
                for (int nh = 0; nh < 2; ++nh)
                    bfr[mi][nh][kh] =
                        B[(kh * 4 + quad) * 64 + mi * 16 + nh * 16 + l16];
            }
        }

        // 12 x v_mfma_f32_16x16x32_f16: D[m=x][n=col] (m89/m120 layout)
        f4 acc[3][2];
        #pragma unroll
        for (int mi = 0; mi < 3; ++mi) {
            #pragma unroll
            for (int nh = 0; nh < 2; ++nh) {
                f4 a = {0.f, 0.f, 0.f, 0.f};
                #pragma unroll
                for (int kh = 0; kh < 2; ++kh)
                    a = __builtin_amdgcn_mfma_f32_16x16x32_f16(
                            afr[mi][kh], bfr[mi][nh][kh], a, 0, 0, 0);
                acc[mi][nh] = a;
            }
        }

        // band extraction: keep |col-x|<=3 -> corr[x][w*7+dx]
        #pragma unroll
        for (int mi = 0; mi < 3; ++mi) {
            #pragma unroll
            for (int nh = 0; nh < 2; ++nh) {
                #pragma unroll
                for (int r = 0; r < 4; ++r) {
                    const int x   = mi * 16 + quad * 4 + r;
                    const int col = mi * 16 + nh * 16 - 8 + l16;
                    const int dx  = col - x + 3;
                    if (x < W_ && dx >= 0 && dx < 7)
                        corr[x][w * 7 + dx] = acc[mi][nh][r] * 0.125f; // 1/sqrt(64)
                }
            }
        }
    }

    __syncthreads();

    // ---- wave 0: softmax over 49 taps + expected flow ----
    if (w == 0) {
        const int xe = min(lane, W_ - 1);
        float c[49];
        float m = -1e30f;
        #pragma unroll
        for (int k = 0; k < 49; ++k) {
            const int kdy = k / 7, kdx = k % 7;
            const int col = lane + kdx - 3;
            const int rr  = y + kdy - 3;
            const bool ok = (col >= 0) && (col < W_) && (rr >= 0) && (rr < H_);
            const float v = ok ? corr[xe][k] : -1e30f;    // mask invalid taps
            c[k] = v;
            m = fmaxf(m, v);
        }
        float S = 0.0f, Sx = 0.0f, Sy = 0.0f;
        #pragma unroll
        for (int k = 0; k < 49; ++k) {
            const float e = __expf(c[k] - m);             // -1e30 -> 0
            S  += e;
            Sx += e * (float)(k % 7 - 3);
            Sy += e * (float)(k / 7 - 3);
        }
        if (lane < W_) {
            const float inv = 1.0f / S;
            // out layout: (n, 2, s, h, w)
            const int ob = (n_idx * 2) * S_ * HW_ + s_idx * HW_ + y * W_ + lane;
            out[ob]            = Sx * inv;                // flow x
            out[ob + S_ * HW_] = Sy * inv;                // flow y
        }
    }
}

extern "C" void kernel_launch(void* const* d_in, const int* in_sizes, int n_in,
                              void* d_out, int out_size, void* d_ws, size_t ws_size,
                              hipStream_t stream) {
    const float* f0 = (const float*)d_in[0];
    const float* f1 = (const float*)d_in[1];
    float* out = (float*)d_out;

    _Float16* pk1 = (_Float16*)d_ws;                       // 4 MB
    _Float16* pk0 = pk1 + (size_t)8 * 64 * 8 * 512;        // +3 MB

    repack_kernel<<<8 * H_, 512, 0, stream>>>(f0, f1, pk0, pk1);
    flow_main<<<8 * H_, 448, 0, stream>>>(pk0, pk1, out);
}